// Round 6
// baseline (6606.461 us; speedup 1.0000x reference)
//
#include <hip/hip_runtime.h>
#include <math.h>

#define B_TOT 2048
#define T_LEN 512
#define HDIM 64
#define FC1 50
#define NBT 128                     // batch tiles of 16 rows
#define RDEPTH 64                   // ring depth in steps
#define RSLOT 1024                  // u32 per slot = 16 rows x 64 units
#define RBT (RDEPTH * RSLOT)        // u32 per (layer,btile) ring
#define RING_TOT (4UL * NBT * RBT)  // 4 inter-layer rings, 128 MiB

typedef __bf16 bf16x8 __attribute__((ext_vector_type(8)));
typedef float f32x4 __attribute__((ext_vector_type(4)));
typedef unsigned int u32x4 __attribute__((ext_vector_type(4)));

__device__ __forceinline__ float sigm(float x) { return 1.0f / (1.0f + __expf(-x)); }
__device__ __forceinline__ float tanh_(float x) { return 2.0f / (1.0f + __expf(-2.0f * x)) - 1.0f; }

// lgkm-only barrier: LDS handoff without draining global queues.
#define BARRIER() asm volatile("s_waitcnt lgkmcnt(0)\n\ts_barrier" ::: "memory")
#define MFMA __builtin_amdgcn_mfma_f32_16x16x32_bf16

__device__ __forceinline__ void unpk(u32x4 p0, u32x4 p1, bf16x8* hi, bf16x8* lo) {
  u32x4 h, l;
  h[0] = __builtin_amdgcn_perm(p0[1], p0[0], 0x05040100u);
  h[1] = __builtin_amdgcn_perm(p0[3], p0[2], 0x05040100u);
  h[2] = __builtin_amdgcn_perm(p1[1], p1[0], 0x05040100u);
  h[3] = __builtin_amdgcn_perm(p1[3], p1[2], 0x05040100u);
  l[0] = __builtin_amdgcn_perm(p0[1], p0[0], 0x07060302u);
  l[1] = __builtin_amdgcn_perm(p0[3], p0[2], 0x07060302u);
  l[2] = __builtin_amdgcn_perm(p1[1], p1[0], 0x07060302u);
  l[3] = __builtin_amdgcn_perm(p1[3], p1[2], 0x07060302u);
  *hi = __builtin_bit_cast(bf16x8, h);
  *lo = __builtin_bit_cast(bf16x8, l);
}

__device__ __forceinline__ void spin_ge(unsigned int* p, unsigned int need) {
  while (__hip_atomic_load(p, __ATOMIC_RELAXED, __HIP_MEMORY_SCOPE_AGENT) < need)
    __builtin_amdgcn_s_sleep(2);
}

// layer-0 x scalars live packed in xpk via bit_cast (overlays mid-layer storage)
#define XPKF_ST(P, idx, val) xpk[P][(idx) >> 2][(idx) & 3] = __builtin_bit_cast(unsigned int, (float)(val))
#define XPKF_LD(P, idx) __builtin_bit_cast(float, xpk[P][(idx) >> 2][(idx) & 3])
#define BIH(g, kk) __builtin_bit_cast(bf16x8, bihr[g][kk])
#define XW(g, i) __builtin_bit_cast(float, bihr[g][0][i])

// One LSTM step. Numerics identical to R3-R5 (absmax 1.22e-4):
// acc[g] = xacc[g] (bias + x-part, computed last step) + 4 chained h-MFMAs;
// epilogue gates fp32; h split to bf16 hi/lo, packed u32, XOR-swizzled LDS.
#define STEP(T0, P)                                                            \
  {                                                                            \
    const int swz = (nn & 7) << 2;                                             \
    bf16x8 ahh0, ahl0, ahh1, ahl1;                                             \
    {                                                                          \
      u32x4 p0 = *(const u32x4*)&hbuf[P][nn * 64 + ((8 * cg) ^ swz)];          \
      u32x4 p1 = *(const u32x4*)&hbuf[P][nn * 64 + ((8 * cg + 4) ^ swz)];      \
      unpk(p0, p1, &ahh0, &ahl0);                                              \
    }                                                                          \
    {                                                                          \
      u32x4 p0 = *(const u32x4*)&hbuf[P][nn * 64 + ((32 + 8 * cg) ^ swz)];     \
      u32x4 p1 = *(const u32x4*)&hbuf[P][nn * 64 + ((32 + 8 * cg + 4) ^ swz)]; \
      unpk(p0, p1, &ahh1, &ahl1);                                              \
    }                                                                          \
    f32x4 accs[4];                                                             \
    _Pragma("unroll")                                                          \
    for (int g = 0; g < 4; ++g) {                                              \
      f32x4 a = xacc[g];                                                       \
      a = MFMA(ahh0, bhh[g][0], a, 0, 0, 0);                                   \
      a = MFMA(ahh1, bhh[g][1], a, 0, 0, 0);                                   \
      a = MFMA(ahl0, bhh[g][0], a, 0, 0, 0);                                   \
      a = MFMA(ahl1, bhh[g][1], a, 0, 0, 0);                                   \
      accs[g] = a;                                                             \
    }                                                                          \
    _Pragma("unroll")                                                          \
    for (int r = 0; r < 4; ++r) {                                              \
      float iv = sigm(accs[0][r]);                                             \
      float fv = sigm(accs[1][r]);                                             \
      float gv = tanh_(accs[2][r]);                                            \
      float ov = sigm(accs[3][r]);                                             \
      cell[r] = fv * cell[r] + iv * gv;                                        \
      float hv = ov * tanh_(cell[r]);                                          \
      __bf16 h1 = (__bf16)hv;                                                  \
      __bf16 h2 = (__bf16)(hv - (float)h1);                                    \
      unsigned int hb = (unsigned int)__builtin_bit_cast(unsigned short, h1)   \
                      | ((unsigned int)__builtin_bit_cast(unsigned short, h2) << 16); \
      int mrow = 4 * cg + r;                                                   \
      hbuf[1 - (P)][mrow * 64 + (uu ^ ((mrow & 7) << 2))] = hb;                \
      if (!isLast) ringW[((T0) & 63) * RSLOT + mrow * 64 + uu] = hb;           \
      else if ((T0) == T_LEN - 1)                                              \
        hT[(size_t)(bbase + mrow) * HDIM + uu] = (float)h1 + (float)h2;        \
    }                                                                          \
    /* off-chain: xacc(T0+1) from xpk[P] (=x(T0+1)); refill xpk[P] = x(T0+3) */\
    if (isFirst) {                                                             \
      _Pragma("unroll")                                                        \
      for (int g = 0; g < 4; ++g) {                                            \
        f32x4 a;                                                               \
        _Pragma("unroll")                                                      \
        for (int r = 0; r < 4; ++r)                                            \
          a[r] = bias[g] + XW(g, 0) * XPKF_LD(P, r * 3 + 0)                    \
                         + XW(g, 1) * XPKF_LD(P, r * 3 + 1)                    \
                         + XW(g, 2) * XPKF_LD(P, r * 3 + 2);                   \
        xacc[g] = a;                                                           \
      }                                                                        \
      int tp = (T0) + 3; if (tp > T_LEN - 1) tp = T_LEN - 1;                   \
      _Pragma("unroll")                                                        \
      for (int r = 0; r < 4; ++r)                                              \
        _Pragma("unroll")                                                      \
        for (int i = 0; i < 3; ++i)                                            \
          XPKF_ST(P, r * 3 + i,                                                \
                  x_f32[((size_t)(bbase + 4 * cg + r) * T_LEN + tp) * 3 + i]); \
    } else {                                                                   \
      bf16x8 xh0, xl0, xh1, xl1;                                               \
      unpk(xpk[P][0], xpk[P][1], &xh0, &xl0);                                  \
      unpk(xpk[P][2], xpk[P][3], &xh1, &xl1);                                  \
      _Pragma("unroll")                                                        \
      for (int g = 0; g < 4; ++g) {                                            \
        f32x4 a = {bias[g], bias[g], bias[g], bias[g]};                        \
        a = MFMA(xh0, BIH(g, 0), a, 0, 0, 0);                                  \
        a = MFMA(xh1, BIH(g, 1), a, 0, 0, 0);                                  \
        a = MFMA(xl0, BIH(g, 0), a, 0, 0, 0);                                  \
        a = MFMA(xl1, BIH(g, 1), a, 0, 0, 0);                                  \
        xacc[g] = a;                                                           \
      }                                                                        \
      const unsigned int* px = ringR + (size_t)(((T0) + 3) & 63) * RSLOT + nn * 64; \
      xpk[P][0] = *(const u32x4*)(px + 8 * cg);                                \
      xpk[P][1] = *(const u32x4*)(px + 8 * cg + 4);                            \
      xpk[P][2] = *(const u32x4*)(px + 32 + 8 * cg);                           \
      xpk[P][3] = *(const u32x4*)(px + 32 + 8 * cg + 4);                       \
    }                                                                          \
    BARRIER();                                                                 \
  }

// 640 blocks = 5 layers x 128 btiles; __launch_bounds__(256,3) => 3 blocks/CU
// guaranteed => all 640 co-resident (768 slots). This is the deadlock-safety
// invariant: do NOT raise VGPR/LDS past it.
__global__ __launch_bounds__(256, 3)
void lstm_pipe(const float* __restrict__ x_f32,
               const float* __restrict__ w_ih0,
               const float* __restrict__ w_ih_rest,
               const float* __restrict__ w_hh,
               const float* __restrict__ b_ih,
               const float* __restrict__ b_hh,
               unsigned int* __restrict__ ring,
               float* __restrict__ hT,
               unsigned int* __restrict__ prog,
               unsigned int* __restrict__ cons)
{
  const int layer = blockIdx.x >> 7;
  const int bt    = blockIdx.x & 127;
  const bool isFirst = (layer == 0);
  const bool isLast  = (layer == 4);
  const int tid  = threadIdx.x;
  const int lane = tid & 63;
  const int wq   = tid >> 6;
  const int nn   = lane & 15;
  const int cg   = lane >> 4;
  const int bbase = bt * 16;
  const int grow = 16 * wq + nn;
  const int uu   = grow;

  __shared__ __align__(16) unsigned int hbuf[2][16 * 64];  // 8 KB

  unsigned int* ringW = ring + ((size_t)layer * NBT + bt) * RBT;               // layer<4
  const unsigned int* ringR = ring + ((size_t)(layer - 1) * NBT + bt) * RBT;   // layer>0
  unsigned int* progW = prog + layer * NBT + bt;
  unsigned int* progR = prog + (layer - 1) * NBT + bt;
  unsigned int* consW = cons + layer * NBT + bt;
  unsigned int* consR = cons + (layer + 1) * NBT + bt;

  // ---- weights ----
  const float* whh_l = w_hh + (size_t)layer * 256 * 64;
  bf16x8 bhh[4][2];
#pragma unroll
  for (int g = 0; g < 4; ++g)
#pragma unroll
    for (int kk = 0; kk < 2; ++kk) {
      const float* wp = whh_l + (size_t)(64 * g + grow) * 64 + kk * 32 + 8 * cg;
      bf16x8 t;
#pragma unroll
      for (int e = 0; e < 8; ++e) t[e] = (__bf16)wp[e];
      bhh[g][kk] = t;
    }
  u32x4 bihr[4][2];
  float bias[4];
#pragma unroll
  for (int g = 0; g < 4; ++g) {
    int row = layer * 256 + 64 * g + grow;
    bias[g] = b_ih[row] + b_hh[row];
  }
  if (isFirst) {
#pragma unroll
    for (int g = 0; g < 4; ++g)
#pragma unroll
      for (int kk = 0; kk < 2; ++kk) bihr[g][kk] = (u32x4){0u, 0u, 0u, 0u};
#pragma unroll
    for (int g = 0; g < 4; ++g)
#pragma unroll
      for (int i = 0; i < 3; ++i)
        bihr[g][0][i] = __builtin_bit_cast(unsigned int, w_ih0[(64 * g + grow) * 3 + i]);
  } else {
    const float* wih_l = w_ih_rest + (size_t)(layer - 1) * 256 * 64;
#pragma unroll
    for (int g = 0; g < 4; ++g)
#pragma unroll
      for (int kk = 0; kk < 2; ++kk) {
        const float* wp = wih_l + (size_t)(64 * g + grow) * 64 + kk * 32 + 8 * cg;
        bf16x8 t;
#pragma unroll
        for (int e = 0; e < 8; ++e) t[e] = (__bf16)wp[e];
        bihr[g][kk] = __builtin_bit_cast(u32x4, t);
      }
  }

  for (int q = tid; q < 16 * 64; q += 256) hbuf[0][q] = 0u;
  float cell[4] = {0.f, 0.f, 0.f, 0.f};
  f32x4 xacc[4];
  u32x4 xpk[2][4];

  // ---- prologue: wait for producer, build xacc(0), prime xpk = x(1), x(2) ----
  if (!isFirst) {
    spin_ge(progR, 16u);
    __builtin_amdgcn_fence(__ATOMIC_ACQUIRE, "agent");
  }
  if (isFirst) {
    float x0[12];
#pragma unroll
    for (int r = 0; r < 4; ++r)
#pragma unroll
      for (int i = 0; i < 3; ++i)
        x0[r * 3 + i] = x_f32[((size_t)(bbase + 4 * cg + r) * T_LEN + 0) * 3 + i];
#pragma unroll
    for (int g = 0; g < 4; ++g) {
      f32x4 a;
#pragma unroll
      for (int r = 0; r < 4; ++r)
        a[r] = bias[g] + XW(g, 0) * x0[r * 3 + 0] + XW(g, 1) * x0[r * 3 + 1]
                       + XW(g, 2) * x0[r * 3 + 2];
      xacc[g] = a;
    }
#pragma unroll
    for (int p = 0; p < 2; ++p)
#pragma unroll
      for (int r = 0; r < 4; ++r)
#pragma unroll
        for (int i = 0; i < 3; ++i) {
          float v = x_f32[((size_t)(bbase + 4 * cg + r) * T_LEN + (p + 1)) * 3 + i];
          if (p == 0) XPKF_ST(0, r * 3 + i, v); else XPKF_ST(1, r * 3 + i, v);
        }
  } else {
    const unsigned int* px = ringR + nn * 64;  // slot 0
    u32x4 q0 = *(const u32x4*)(px + 8 * cg);
    u32x4 q1 = *(const u32x4*)(px + 8 * cg + 4);
    u32x4 q2 = *(const u32x4*)(px + 32 + 8 * cg);
    u32x4 q3 = *(const u32x4*)(px + 32 + 8 * cg + 4);
    bf16x8 xh0, xl0, xh1, xl1;
    unpk(q0, q1, &xh0, &xl0);
    unpk(q2, q3, &xh1, &xl1);
#pragma unroll
    for (int g = 0; g < 4; ++g) {
      f32x4 a = {bias[g], bias[g], bias[g], bias[g]};
      a = MFMA(xh0, BIH(g, 0), a, 0, 0, 0);
      a = MFMA(xh1, BIH(g, 1), a, 0, 0, 0);
      a = MFMA(xl0, BIH(g, 0), a, 0, 0, 0);
      a = MFMA(xl1, BIH(g, 1), a, 0, 0, 0);
      xacc[g] = a;
    }
#pragma unroll
    for (int p = 0; p < 2; ++p) {
      const unsigned int* pq = ringR + (size_t)(p + 1) * RSLOT + nn * 64;
      xpk[p][0] = *(const u32x4*)(pq + 8 * cg);
      xpk[p][1] = *(const u32x4*)(pq + 8 * cg + 4);
      xpk[p][2] = *(const u32x4*)(pq + 32 + 8 * cg);
      xpk[p][3] = *(const u32x4*)(pq + 32 + 8 * cg + 4);
    }
  }
  __syncthreads();

  // ---- main loop: groups of 8 steps, flags every group ----
  // consumer reads in group [s,s+8) touch slots <= s+10  -> need prog >= s+16 (quantized).
  // producer writes slots [s,s+8) reuse step s-64 data    -> need cons >= s-56.
  for (int s = 0; s < T_LEN; s += 8) {
    if (!isFirst && s) {
      unsigned need = (unsigned)(s + 16 > T_LEN ? T_LEN : s + 16);
      spin_ge(progR, need);
      __builtin_amdgcn_fence(__ATOMIC_ACQUIRE, "agent");
    }
    if (!isLast && s >= RDEPTH) spin_ge(consR, (unsigned)(s + 8 - RDEPTH));

    STEP(s + 0, 0); STEP(s + 1, 1); STEP(s + 2, 0); STEP(s + 3, 1);
    STEP(s + 4, 0); STEP(s + 5, 1); STEP(s + 6, 0); STEP(s + 7, 1);

    __builtin_amdgcn_fence(__ATOMIC_RELEASE, "agent");  // vmcnt0 + wbL2, all threads
    __builtin_amdgcn_s_barrier();                       // all threads fenced
    if (tid == 0) {
      if (!isLast)
        __hip_atomic_store(progW, (unsigned)(s + 8), __ATOMIC_RELAXED, __HIP_MEMORY_SCOPE_AGENT);
      if (!isFirst)
        __hip_atomic_store(consW, (unsigned)(s + 8), __ATOMIC_RELAXED, __HIP_MEMORY_SCOPE_AGENT);
    }
  }
}

__global__ void init_flags(unsigned int* f, int n) {
  int i = blockIdx.x * 256 + threadIdx.x;
  if (i < n) f[i] = 0u;
}

// FC head: out[b] = fc2_b + fc2_w . relu(fc1_b + fc1_w . hT[b])
__global__ __launch_bounds__(256, 1)
void fc_head(const float* __restrict__ hT,
             const float* __restrict__ fc1_w, const float* __restrict__ fc1_b,
             const float* __restrict__ fc2_w, const float* __restrict__ fc2_b,
             float* __restrict__ out)
{
    __shared__ float w1[FC1 * HDIM];
    __shared__ float b1[FC1];
    __shared__ float w2[FC1];
    const int tid = threadIdx.x;
    for (int i = tid; i < FC1 * HDIM; i += 256) w1[i] = fc1_w[i];
    if (tid < FC1) { b1[tid] = fc1_b[tid]; w2[tid] = fc2_w[tid]; }
    __syncthreads();

    const int b = blockIdx.x * 256 + tid;
    float h[HDIM];
#pragma unroll
    for (int q = 0; q < HDIM; ++q) h[q] = hT[(size_t)b * HDIM + q];
    float acc2 = fc2_b[0];
    for (int m = 0; m < FC1; ++m) {
      float a = b1[m];
#pragma unroll
      for (int q = 0; q < HDIM; ++q) a += w1[m * HDIM + q] * h[q];
      acc2 += w2[m] * fmaxf(a, 0.0f);
    }
    out[b] = acc2;
}

extern "C" void kernel_launch(void* const* d_in, const int* in_sizes, int n_in,
                              void* d_out, int out_size, void* d_ws, size_t ws_size,
                              hipStream_t stream) {
    const float* x         = (const float*)d_in[0];
    const float* w_ih0     = (const float*)d_in[1];
    const float* w_ih_rest = (const float*)d_in[2];
    const float* w_hh      = (const float*)d_in[3];
    const float* b_ih      = (const float*)d_in[4];
    const float* b_hh      = (const float*)d_in[5];
    const float* fc1_w     = (const float*)d_in[6];
    const float* fc1_b     = (const float*)d_in[7];
    const float* fc2_w     = (const float*)d_in[8];
    const float* fc2_b     = (const float*)d_in[9];
    float* out = (float*)d_out;

    unsigned int* ring = (unsigned int*)d_ws;                 // 128 MiB
    float* hT = (float*)(ring + RING_TOT);                    // 512 KiB
    unsigned int* flags = (unsigned int*)(hT + (size_t)B_TOT * HDIM);
    unsigned int* prog = flags;                               // [5][128]
    unsigned int* cons = flags + 5 * NBT;                     // [5][128]

    init_flags<<<dim3(5), dim3(256), 0, stream>>>(flags, 2 * 5 * NBT);
    lstm_pipe<<<dim3(5 * NBT), dim3(256), 0, stream>>>(
        x, w_ih0, w_ih_rest, w_hh, b_ih, b_hh, ring, hT, prog, cons);
    fc_head<<<dim3(B_TOT / 256), dim3(256), 0, stream>>>(
        hT, fc1_w, fc1_b, fc2_w, fc2_b, out);
}

// Round 7
// 3860.356 us; speedup vs baseline: 1.7114x; 1.7114x over previous
//
#include <hip/hip_runtime.h>
#include <math.h>

#define B_TOT 2048
#define T_LEN 512
#define HDIM 64
#define FC1 50
#define NSUPER 516   // 512 + skew(<=2) padded to multiple of 4

typedef __bf16 bf16x8 __attribute__((ext_vector_type(8)));
typedef float f32x4 __attribute__((ext_vector_type(4)));
typedef unsigned int u32x4 __attribute__((ext_vector_type(4)));

__device__ __forceinline__ float sigm(float x) { return 1.0f / (1.0f + __expf(-x)); }
__device__ __forceinline__ float tanh_(float x) { return 2.0f / (1.0f + __expf(-2.0f * x)) - 1.0f; }

// lgkm-only barrier: LDS visibility without draining global loads/stores.
#define BARRIER() asm volatile("s_waitcnt lgkmcnt(0)\n\ts_barrier" ::: "memory")
#define MFMA __builtin_amdgcn_mfma_f32_16x16x32_bf16

__device__ __forceinline__ void unpk(u32x4 p0, u32x4 p1, bf16x8* hi, bf16x8* lo) {
  u32x4 h, l;
  h[0] = __builtin_amdgcn_perm(p0[1], p0[0], 0x05040100u);
  h[1] = __builtin_amdgcn_perm(p0[3], p0[2], 0x05040100u);
  h[2] = __builtin_amdgcn_perm(p1[1], p1[0], 0x05040100u);
  h[3] = __builtin_amdgcn_perm(p1[3], p1[2], 0x05040100u);
  l[0] = __builtin_amdgcn_perm(p0[1], p0[0], 0x07060302u);
  l[1] = __builtin_amdgcn_perm(p0[3], p0[2], 0x07060302u);
  l[2] = __builtin_amdgcn_perm(p1[1], p1[0], 0x07060302u);
  l[3] = __builtin_amdgcn_perm(p1[3], p1[2], 0x07060302u);
  *hi = __builtin_bit_cast(bf16x8, h);
  *lo = __builtin_bit_cast(bf16x8, l);
}

// Intra-block skewed layer pipeline. Block = 16 batch rows x NSETS layer-sets.
// Set s (4 waves) owns layer BASE+s; at superstep n it computes its layer's
// time tl = n - s. Handoff h between sets via per-set double-parity LDS
// buffers (packed bf16 hi|lo<<16, XOR-swizzled) -- written to [1-P] at n,
// read by downstream at n+1 from [P']. ONE lgkm barrier per superstep.
// Numerics identical to R3-R5 (absmax 1.22e-4): seed = bias + x-part
// (scalar FMA for L0 / 4 MFMAs otherwise), then 4 chained W_hh MFMAs,
// fp32 gates, fp32 cell, h split to bf16 hi+lo.
#define STEPF(N_, P_, S_)                                                      \
  {                                                                            \
    const int tl = (N_) - set;                                                 \
    if (tl >= 0 && tl < T_LEN) {                                               \
      const int swz = (nn & 7) << 2;                                           \
      const unsigned int* hb = &hbuf[set][P_][0];                              \
      bf16x8 ahh0, ahl0, ahh1, ahl1;                                           \
      { u32x4 p0 = *(const u32x4*)&hb[nn * 64 + ((8 * cg) ^ swz)];             \
        u32x4 p1 = *(const u32x4*)&hb[nn * 64 + ((8 * cg + 4) ^ swz)];         \
        unpk(p0, p1, &ahh0, &ahl0); }                                          \
      { u32x4 p0 = *(const u32x4*)&hb[nn * 64 + ((32 + 8 * cg) ^ swz)];        \
        u32x4 p1 = *(const u32x4*)&hb[nn * 64 + ((32 + 8 * cg + 4) ^ swz)];    \
        unpk(p0, p1, &ahh1, &ahl1); }                                          \
      f32x4 accs[4];                                                           \
      if (roleL0) {                                                            \
        _Pragma("unroll") for (int g = 0; g < 4; ++g) {                        \
          f32x4 a;                                                             \
          _Pragma("unroll") for (int r = 0; r < 4; ++r)                        \
            a[r] = bias[g] + xw[g*3+0] * xr[P_][r*3+0]                         \
                           + xw[g*3+1] * xr[P_][r*3+1]                         \
                           + xw[g*3+2] * xr[P_][r*3+2];                        \
          accs[g] = a;                                                         \
        }                                                                      \
      } else {                                                                 \
        bf16x8 xh0, xl0, xh1, xl1;                                             \
        if (IN_GLB && set == 0) {                                              \
          unpk(xq[S_][P_][0], xq[S_][P_][1], &xh0, &xl0);                      \
          unpk(xq[S_][P_][2], xq[S_][P_][3], &xh1, &xl1);                      \
        } else {                                                               \
          const unsigned int* ub = &hbuf[set - 1][P_][0];                      \
          u32x4 q0 = *(const u32x4*)&ub[nn * 64 + ((8 * cg) ^ swz)];           \
          u32x4 q1 = *(const u32x4*)&ub[nn * 64 + ((8 * cg + 4) ^ swz)];       \
          u32x4 q2 = *(const u32x4*)&ub[nn * 64 + ((32 + 8 * cg) ^ swz)];      \
          u32x4 q3 = *(const u32x4*)&ub[nn * 64 + ((32 + 8 * cg + 4) ^ swz)];  \
          unpk(q0, q1, &xh0, &xl0);                                            \
          unpk(q2, q3, &xh1, &xl1);                                            \
        }                                                                      \
        _Pragma("unroll") for (int g = 0; g < 4; ++g) {                        \
          f32x4 a = {bias[g], bias[g], bias[g], bias[g]};                      \
          a = MFMA(xh0, bih[g][0], a, 0, 0, 0);                                \
          a = MFMA(xh1, bih[g][1], a, 0, 0, 0);                                \
          a = MFMA(xl0, bih[g][0], a, 0, 0, 0);                                \
          a = MFMA(xl1, bih[g][1], a, 0, 0, 0);                                \
          accs[g] = a;                                                         \
        }                                                                      \
      }                                                                        \
      _Pragma("unroll") for (int g = 0; g < 4; ++g) {                          \
        f32x4 a = accs[g];                                                     \
        a = MFMA(ahh0, bhh[g][0], a, 0, 0, 0);                                 \
        a = MFMA(ahh1, bhh[g][1], a, 0, 0, 0);                                 \
        a = MFMA(ahl0, bhh[g][0], a, 0, 0, 0);                                 \
        a = MFMA(ahl1, bhh[g][1], a, 0, 0, 0);                                 \
        accs[g] = a;                                                           \
      }                                                                        \
      unsigned int* ho = &hbuf[set][1 - (P_)][0];                              \
      _Pragma("unroll") for (int r = 0; r < 4; ++r) {                          \
        float iv = sigm(accs[0][r]);                                           \
        float fv = sigm(accs[1][r]);                                           \
        float gv = tanh_(accs[2][r]);                                          \
        float ov = sigm(accs[3][r]);                                           \
        cell[r] = fv * cell[r] + iv * gv;                                      \
        float hv = ov * tanh_(cell[r]);                                        \
        __bf16 h1 = (__bf16)hv;                                                \
        __bf16 h2 = (__bf16)(hv - (float)h1);                                  \
        unsigned int hpk = (unsigned int)__builtin_bit_cast(unsigned short, h1)\
                         | ((unsigned int)__builtin_bit_cast(unsigned short, h2) << 16); \
        int mrow = 4 * cg + r;                                                 \
        ho[mrow * 64 + (uu ^ ((mrow & 7) << 2))] = hpk;                        \
        if (OUT_GLB && set == NSETS - 1)                                       \
          seqp[((size_t)(bbase + mrow) * T_LEN + tl) * HDIM + uu] = hpk;       \
        if (BASE + NSETS == 5 && set == NSETS - 1 && tl == T_LEN - 1)          \
          ((float*)seqp)[(size_t)(bbase + mrow) * T_LEN * HDIM + uu] =         \
              (float)h1 + (float)h2;                                           \
      }                                                                        \
      if (roleL0) {                                                            \
        int tp = tl + 2; if (tp > T_LEN - 1) tp = T_LEN - 1;                   \
        _Pragma("unroll") for (int r = 0; r < 4; ++r)                          \
          _Pragma("unroll") for (int i = 0; i < 3; ++i)                        \
            xr[P_][r*3+i] =                                                    \
                x_f32[((size_t)(bbase + 4 * cg + r) * T_LEN + tp) * 3 + i];    \
      }                                                                        \
      if (IN_GLB && set == 0) {                                                \
        int tp = tl + 4; if (tp > T_LEN - 1) tp = T_LEN - 1;                   \
        const unsigned int* px = seqp + xrow + (size_t)tp * HDIM;              \
        xq[S_][P_][0] = *(const u32x4*)(px + 8 * cg);                          \
        xq[S_][P_][1] = *(const u32x4*)(px + 8 * cg + 4);                      \
        xq[S_][P_][2] = *(const u32x4*)(px + 32 + 8 * cg);                     \
        xq[S_][P_][3] = *(const u32x4*)(px + 32 + 8 * cg + 4);                 \
      }                                                                        \
    }                                                                          \
    BARRIER();                                                                 \
  }

// Kernel A: BASE=0, NSETS=3 (layers 0-2), OUT_GLB -> seqp (packed h2).
// Kernel B: BASE=3, NSETS=2 (layers 3-4), IN_GLB <- seqp, writes hT (f32)
//           into the seqp[b][0][:] region (consumed by set 0 only at n<4).
template<int BASE, int NSETS, bool IN_GLB, bool OUT_GLB, int WPE>
__global__ __launch_bounds__(NSETS * 256, WPE)
void lstm_fused(const float* __restrict__ x_f32,
                const float* __restrict__ w_ih0,
                const float* __restrict__ w_ih_rest,
                const float* __restrict__ w_hh,
                const float* __restrict__ b_ih,
                const float* __restrict__ b_hh,
                unsigned int* __restrict__ seqp)
{
  const int tid  = threadIdx.x;
  const int lane = tid & 63;
  const int wv   = tid >> 6;
  const int set  = wv >> 2;       // layer-set 0..NSETS-1 (wave-uniform)
  const int wq   = wv & 3;        // 16-unit column block within the layer
  const int nn   = lane & 15;     // A-row m (batch) / B-col n (gate col)
  const int cg   = lane >> 4;     // k-group / D row group
  const int bbase = blockIdx.x * 16;
  const int grow = 16 * wq + nn;  // unit index
  const int uu   = grow;
  const int layer = BASE + set;
  const bool roleL0 = (BASE == 0) && (set == 0);

  __shared__ __align__(16) unsigned int hbuf[NSETS][2][1024];  // 8KB/set

  // ---- weights (bf16 B-fragments, in VGPRs for the whole kernel) ----
  bf16x8 bhh[4][2];
#pragma unroll
  for (int g = 0; g < 4; ++g)
#pragma unroll
    for (int kk = 0; kk < 2; ++kk) {
      const float* wp = w_hh + (size_t)layer * 256 * 64
                      + (size_t)(64 * g + grow) * 64 + kk * 32 + 8 * cg;
      bf16x8 t;
#pragma unroll
      for (int e = 0; e < 8; ++e) t[e] = (__bf16)wp[e];
      bhh[g][kk] = t;
    }
  bf16x8 bih[4][2];
  float xw[12];
  if (roleL0) {
#pragma unroll
    for (int g = 0; g < 4; ++g)
#pragma unroll
      for (int i = 0; i < 3; ++i) xw[g * 3 + i] = w_ih0[(64 * g + grow) * 3 + i];
  } else {
#pragma unroll
    for (int g = 0; g < 4; ++g)
#pragma unroll
      for (int kk = 0; kk < 2; ++kk) {
        const float* wp = w_ih_rest + (size_t)(layer - 1) * 256 * 64
                        + (size_t)(64 * g + grow) * 64 + kk * 32 + 8 * cg;
        bf16x8 t;
#pragma unroll
        for (int e = 0; e < 8; ++e) t[e] = (__bf16)wp[e];
        bih[g][kk] = t;
      }
  }
  float bias[4];
#pragma unroll
  for (int g = 0; g < 4; ++g) {
    int row = layer * 256 + 64 * g + grow;
    bias[g] = b_ih[row] + b_hh[row];
  }

  // zero both parities of all h-buffers (h(-1) = 0)
  for (int q = tid; q < NSETS * 2 * 1024; q += NSETS * 256)
    ((unsigned int*)hbuf)[q] = 0u;

  float cell[4] = {0.f, 0.f, 0.f, 0.f};
  const size_t xrow = (size_t)(bbase + nn) * T_LEN * HDIM;

  float xr[2][12];      // L0 x queue, depth 2 (dead in kernel B)
  u32x4 xq[2][2][4];    // global h-queue, depth 4 (dead in kernel A)
  if (roleL0) {
#pragma unroll
    for (int t = 0; t < 2; ++t)
#pragma unroll
      for (int r = 0; r < 4; ++r)
#pragma unroll
        for (int i = 0; i < 3; ++i)
          xr[t][r * 3 + i] = x_f32[((size_t)(bbase + 4 * cg + r) * T_LEN + t) * 3 + i];
  }
  if (IN_GLB && set == 0) {
#pragma unroll
    for (int t = 0; t < 4; ++t) {
      const unsigned int* px = seqp + xrow + (size_t)t * HDIM;
      xq[(t >> 1) & 1][t & 1][0] = *(const u32x4*)(px + 8 * cg);
      xq[(t >> 1) & 1][t & 1][1] = *(const u32x4*)(px + 8 * cg + 4);
      xq[(t >> 1) & 1][t & 1][2] = *(const u32x4*)(px + 32 + 8 * cg);
      xq[(t >> 1) & 1][t & 1][3] = *(const u32x4*)(px + 32 + 8 * cg + 4);
    }
  }
  __syncthreads();

  for (int n = 0; n < NSUPER; n += 4) {
    STEPF(n,     0, 0);
    STEPF(n + 1, 1, 0);
    STEPF(n + 2, 0, 1);
    STEPF(n + 3, 1, 1);
  }
}

// FC head: out[b] = fc2_b + fc2_w . relu(fc1_b + fc1_w . hT[b])
// hT (f32) lives in the seqp[b][0][:] region.
__global__ __launch_bounds__(256, 1)
void fc_head(const unsigned int* __restrict__ seqp,
             const float* __restrict__ fc1_w, const float* __restrict__ fc1_b,
             const float* __restrict__ fc2_w, const float* __restrict__ fc2_b,
             float* __restrict__ out)
{
    __shared__ float w1[FC1 * HDIM];
    __shared__ float b1[FC1];
    __shared__ float w2[FC1];
    const int tid = threadIdx.x;
    for (int i = tid; i < FC1 * HDIM; i += 256) w1[i] = fc1_w[i];
    if (tid < FC1) { b1[tid] = fc1_b[tid]; w2[tid] = fc2_w[tid]; }
    __syncthreads();

    const int b = blockIdx.x * 256 + tid;
    const float* hT = (const float*)seqp;
    float h[HDIM];
#pragma unroll
    for (int q = 0; q < HDIM; ++q) h[q] = hT[(size_t)b * T_LEN * HDIM + q];
    float acc2 = fc2_b[0];
    for (int m = 0; m < FC1; ++m) {
      float a = b1[m];
#pragma unroll
      for (int q = 0; q < HDIM; ++q) a += w1[m * HDIM + q] * h[q];
      acc2 += w2[m] * fmaxf(a, 0.0f);
    }
    out[b] = acc2;
}

extern "C" void kernel_launch(void* const* d_in, const int* in_sizes, int n_in,
                              void* d_out, int out_size, void* d_ws, size_t ws_size,
                              hipStream_t stream) {
    const float* x         = (const float*)d_in[0];
    const float* w_ih0     = (const float*)d_in[1];
    const float* w_ih_rest = (const float*)d_in[2];
    const float* w_hh      = (const float*)d_in[3];
    const float* b_ih      = (const float*)d_in[4];
    const float* b_hh      = (const float*)d_in[5];
    const float* fc1_w     = (const float*)d_in[6];
    const float* fc1_b     = (const float*)d_in[7];
    const float* fc2_w     = (const float*)d_in[8];
    const float* fc2_b     = (const float*)d_in[9];
    float* out = (float*)d_out;

    unsigned int* seqp = (unsigned int*)d_ws;   // [B,T,64] packed h2 = 256 MiB

    // layers 0-2, intra-block pipelined; writes packed h2 seq
    lstm_fused<0, 3, false, true, 3><<<dim3(B_TOT / 16), dim3(768), 0, stream>>>(
        x, w_ih0, w_ih_rest, w_hh, b_ih, b_hh, seqp);
    // layers 3-4; reads h2 seq (depth-4 prefetch), writes hT f32 into seqp[:,0,:]
    lstm_fused<3, 2, true, false, 2><<<dim3(B_TOT / 16), dim3(512), 0, stream>>>(
        x, w_ih0, w_ih_rest, w_hh, b_ih, b_hh, seqp);
    fc_head<<<dim3(B_TOT / 256), dim3(256), 0, stream>>>(
        seqp, fc1_w, fc1_b, fc2_w, fc2_b, out);
}

// Round 8
// 2592.231 us; speedup vs baseline: 2.5486x; 1.4892x over previous
//
#include <hip/hip_runtime.h>
#include <math.h>

#define B_TOT 2048
#define T_LEN 512
#define HDIM 64
#define FC1 50

typedef __bf16 bf16x8 __attribute__((ext_vector_type(8)));
typedef float f32x4 __attribute__((ext_vector_type(4)));
typedef unsigned int u32x4 __attribute__((ext_vector_type(4)));

__device__ __forceinline__ float sigm(float x) { return 1.0f / (1.0f + __expf(-x)); }
__device__ __forceinline__ float tanh_(float x) { return 2.0f / (1.0f + __expf(-2.0f * x)) - 1.0f; }

// lgkm-only barrier: LDS visibility without draining global loads/stores.
#define BARRIER() asm volatile("s_waitcnt lgkmcnt(0)\n\ts_barrier" ::: "memory")
#define MFMA __builtin_amdgcn_mfma_f32_16x16x32_bf16

// Planar h-exchange addressing: row-major [16][64] bf16 with 16B-chunk XOR
// swizzle (chunk ^= row&7): a full-wave b128 read lands exactly 8 lanes per
// 4-bank group = the unavoidable minimum (conflict-free-equivalent, m136).
#define HADDR(row, chunk) (((row) << 6) + ((((chunk) ^ ((row) & 7))) << 3))

__device__ __forceinline__ void unpk(u32x4 p0, u32x4 p1, bf16x8* hi, bf16x8* lo) {
  u32x4 h, l;
  h[0] = __builtin_amdgcn_perm(p0[1], p0[0], 0x05040100u);
  h[1] = __builtin_amdgcn_perm(p0[3], p0[2], 0x05040100u);
  h[2] = __builtin_amdgcn_perm(p1[1], p1[0], 0x05040100u);
  h[3] = __builtin_amdgcn_perm(p1[3], p1[2], 0x05040100u);
  l[0] = __builtin_amdgcn_perm(p0[1], p0[0], 0x07060302u);
  l[1] = __builtin_amdgcn_perm(p0[3], p0[2], 0x07060302u);
  l[2] = __builtin_amdgcn_perm(p1[1], p1[0], 0x07060302u);
  l[3] = __builtin_amdgcn_perm(p1[3], p1[2], 0x07060302u);
  *hi = __builtin_bit_cast(bf16x8, h);
  *lo = __builtin_bit_cast(bf16x8, l);
}

// Producer/consumer split LSTM step (R5 structure, planar h-exchange).
// Waves 0-3 (A, prio 1): recurrence — 4 planar ds_read_b128 (NO unpack on the
//   chain), 16 h-MFMAs seeded from accx[P] (bias + x-part from B), fp32 gate
//   epilogue, 8 ds_write_b16 planar h (no pack).
// Waves 4-7 (B, prio 0): read planar h(t-1), pack, store to global seq;
//   x-MFMAs for t+1 into accx[1-P]; prefetch packed x(t+3).
// Numerics bit-identical to R3-R5 (absmax 1.2207e-4).
#define STEP(T0, P)                                                            \
  {                                                                            \
    if (isA) {                                                                 \
      bf16x8 ahh0 = *(const bf16x8*)&h_hi[P][HADDR(nn, cg)];                   \
      bf16x8 ahh1 = *(const bf16x8*)&h_hi[P][HADDR(nn, 4 + cg)];               \
      bf16x8 ahl0 = *(const bf16x8*)&h_lo[P][HADDR(nn, cg)];                   \
      bf16x8 ahl1 = *(const bf16x8*)&h_lo[P][HADDR(nn, 4 + cg)];               \
      f32x4 accs[4];                                                           \
      _Pragma("unroll")                                                        \
      for (int g = 0; g < 4; ++g) {                                            \
        f32x4 a = accx[P][g][wq * 64 + lane];                                  \
        a = MFMA(ahh0, bhh[g][0], a, 0, 0, 0);                                 \
        a = MFMA(ahh1, bhh[g][1], a, 0, 0, 0);                                 \
        a = MFMA(ahl0, bhh[g][0], a, 0, 0, 0);                                 \
        a = MFMA(ahl1, bhh[g][1], a, 0, 0, 0);                                 \
        accs[g] = a;                                                           \
      }                                                                        \
      _Pragma("unroll")                                                        \
      for (int r = 0; r < 4; ++r) {                                            \
        float iv = sigm(accs[0][r]);                                           \
        float fv = sigm(accs[1][r]);                                           \
        float gv = tanh_(accs[2][r]);                                          \
        float ov = sigm(accs[3][r]);                                           \
        cell[r] = fv * cell[r] + iv * gv;                                      \
        float hv = ov * tanh_(cell[r]);                                        \
        __bf16 h1 = (__bf16)hv;                                                \
        __bf16 h2 = (__bf16)(hv - (float)h1);                                  \
        int mrow = 4 * cg + r;                                                 \
        int ha = HADDR(mrow, uu >> 3) + (uu & 7);                              \
        h_hi[1 - (P)][ha] = h1;                                                \
        h_lo[1 - (P)][ha] = h2;                                                \
      }                                                                        \
    } else {                                                                   \
      if ((T0) > 0) {                                                          \
        _Pragma("unroll")                                                      \
        for (int r = 0; r < 4; ++r) {                                          \
          int mrow = 4 * cg + r;                                               \
          int ha = HADDR(mrow, uu >> 3) + (uu & 7);                            \
          unsigned int hb =                                                    \
              (unsigned int)__builtin_bit_cast(unsigned short, h_hi[P][ha])    \
            | ((unsigned int)__builtin_bit_cast(unsigned short, h_lo[P][ha]) << 16); \
          seqp[((size_t)(bbase + mrow) * T_LEN + (T0) - 1) * HDIM + uu] = hb;  \
        }                                                                      \
      }                                                                        \
      if ((T0) + 1 < T_LEN) {                                                  \
        if (FIRST) {                                                           \
          _Pragma("unroll")                                                    \
          for (int g = 0; g < 4; ++g) {                                        \
            f32x4 a;                                                           \
            _Pragma("unroll")                                                  \
            for (int r = 0; r < 4; ++r)                                        \
              a[r] = bias[g] + xw[g*3+0] * xr[P][r*3+0]                        \
                             + xw[g*3+1] * xr[P][r*3+1]                        \
                             + xw[g*3+2] * xr[P][r*3+2];                       \
            accx[1 - (P)][g][wq * 64 + lane] = a;                              \
          }                                                                    \
        } else {                                                               \
          bf16x8 xh0, xl0, xh1, xl1;                                           \
          unpk(xpk[P][0], xpk[P][1], &xh0, &xl0);                              \
          unpk(xpk[P][2], xpk[P][3], &xh1, &xl1);                              \
          _Pragma("unroll")                                                    \
          for (int g = 0; g < 4; ++g) {                                        \
            f32x4 a = {bias[g], bias[g], bias[g], bias[g]};                    \
            a = MFMA(xh0, bih[g][0], a, 0, 0, 0);                              \
            a = MFMA(xh1, bih[g][1], a, 0, 0, 0);                              \
            a = MFMA(xl0, bih[g][0], a, 0, 0, 0);                              \
            a = MFMA(xl1, bih[g][1], a, 0, 0, 0);                              \
            accx[1 - (P)][g][wq * 64 + lane] = a;                              \
          }                                                                    \
        }                                                                      \
      }                                                                        \
      {                                                                        \
        int tp = (T0) + 3; if (tp >= T_LEN) tp = T_LEN - 1;                    \
        if (FIRST) {                                                           \
          _Pragma("unroll")                                                    \
          for (int r = 0; r < 4; ++r)                                          \
            _Pragma("unroll")                                                  \
            for (int i = 0; i < 3; ++i)                                        \
              xr[P][r*3+i] = x_f32[((size_t)(bbase + 4*cg + r) * T_LEN + tp) * 3 + i]; \
        } else {                                                               \
          const unsigned int* px = seqp + xrow + (size_t)tp * HDIM;            \
          xpk[P][0] = *(const u32x4*)(px + 8 * cg);                            \
          xpk[P][1] = *(const u32x4*)(px + 8 * cg + 4);                        \
          xpk[P][2] = *(const u32x4*)(px + 32 + 8 * cg);                       \
          xpk[P][3] = *(const u32x4*)(px + 32 + 8 * cg + 4);                   \
        }                                                                      \
      }                                                                        \
    }                                                                          \
    BARRIER();                                                                 \
  }

template<bool FIRST>
__global__ __launch_bounds__(512, 2)
void lstm_mfma(const float* __restrict__ x_f32,  // FIRST only: [B,T,3] f32
               const float* __restrict__ w_ih,   // FIRST: [256,3] else [256,64]
               const float* __restrict__ w_hh,   // [256,64]
               const float* __restrict__ b_ih,   // [256]
               const float* __restrict__ b_hh,   // [256]
               unsigned int* seqp)               // [B,T,64] packed hi|lo<<16 (in-place for mid)
{
    const int tid  = threadIdx.x;
    const int lane = tid & 63;
    const int wv   = tid >> 6;      // 0..7
    const bool isA = (wv < 4);
    const int wq   = wv & 3;        // unit-block index within group
    const int nn   = lane & 15;     // A-row m (batch) / B-col n (gate col)
    const int cg   = lane >> 4;     // k-group / D row group
    const int bbase = blockIdx.x * 16;
    const int grow = 16 * wq + nn;  // unit / gate-col index
    const int uu   = grow;

    __shared__ __align__(16) __bf16 h_hi[2][16 * 64];   // 2 KB, planar+swizzled
    __shared__ __align__(16) __bf16 h_lo[2][16 * 64];   // 2 KB
    __shared__ __align__(16) f32x4 accx[2][4][256];     // 32 KB

    // ---- weights ----
    bf16x8 bhh[4][2];
    bf16x8 bih[4][2];
    float xw[12];
    float bias[4];
    if (isA) {
#pragma unroll
      for (int g = 0; g < 4; ++g)
#pragma unroll
        for (int kk = 0; kk < 2; ++kk) {
          const float* wp = w_hh + (size_t)(64 * g + grow) * 64 + kk * 32 + 8 * cg;
          bf16x8 t;
#pragma unroll
          for (int e = 0; e < 8; ++e) t[e] = (__bf16)wp[e];
          bhh[g][kk] = t;
        }
    } else {
#pragma unroll
      for (int g = 0; g < 4; ++g) {
        int row = 64 * g + grow;
        bias[g] = b_ih[row] + b_hh[row];
      }
      if (FIRST) {
#pragma unroll
        for (int g = 0; g < 4; ++g)
#pragma unroll
          for (int i = 0; i < 3; ++i) xw[g * 3 + i] = w_ih[(64 * g + grow) * 3 + i];
      } else {
#pragma unroll
        for (int g = 0; g < 4; ++g)
#pragma unroll
          for (int kk = 0; kk < 2; ++kk) {
            const float* wp = w_ih + (size_t)(64 * g + grow) * 64 + kk * 32 + 8 * cg;
            bf16x8 t;
#pragma unroll
            for (int e = 0; e < 8; ++e) t[e] = (__bf16)wp[e];
            bih[g][kk] = t;
          }
      }
    }

    // zero h(-1) (both parities, both planes)
    for (int q = tid; q < 1024; q += 512) {
      h_hi[0][q] = (__bf16)0.f; h_hi[1][q] = (__bf16)0.f;
      h_lo[0][q] = (__bf16)0.f; h_lo[1][q] = (__bf16)0.f;
    }

    float cell[4] = {0.f, 0.f, 0.f, 0.f};

    const size_t xrow = (size_t)(bbase + nn) * T_LEN * HDIM;
    u32x4 xpk[2][4];
    float xr[2][12];

    if (!isA) {
      // ---- prologue: accx[0] from x(0); prime xr/xpk = x(1), x(2) ----
      if (FIRST) {
        float x0[12];
#pragma unroll
        for (int r = 0; r < 4; ++r)
#pragma unroll
          for (int i = 0; i < 3; ++i)
            x0[r*3+i] = x_f32[((size_t)(bbase + 4*cg + r) * T_LEN + 0) * 3 + i];
#pragma unroll
        for (int g = 0; g < 4; ++g) {
          f32x4 a;
#pragma unroll
          for (int r = 0; r < 4; ++r)
            a[r] = bias[g] + xw[g*3+0]*x0[r*3+0] + xw[g*3+1]*x0[r*3+1] + xw[g*3+2]*x0[r*3+2];
          accx[0][g][wq * 64 + lane] = a;
        }
#pragma unroll
        for (int p = 0; p < 2; ++p)
#pragma unroll
          for (int r = 0; r < 4; ++r)
#pragma unroll
            for (int i = 0; i < 3; ++i)
              xr[p][r*3+i] = x_f32[((size_t)(bbase + 4*cg + r) * T_LEN + (p + 1)) * 3 + i];
      } else {
        const unsigned int* px = seqp + xrow;
        u32x4 q0 = *(const u32x4*)(px + 8 * cg);
        u32x4 q1 = *(const u32x4*)(px + 8 * cg + 4);
        u32x4 q2 = *(const u32x4*)(px + 32 + 8 * cg);
        u32x4 q3 = *(const u32x4*)(px + 32 + 8 * cg + 4);
        bf16x8 xh0, xl0, xh1, xl1;
        unpk(q0, q1, &xh0, &xl0);
        unpk(q2, q3, &xh1, &xl1);
#pragma unroll
        for (int g = 0; g < 4; ++g) {
          f32x4 a = {bias[g], bias[g], bias[g], bias[g]};
          a = MFMA(xh0, bih[g][0], a, 0, 0, 0);
          a = MFMA(xh1, bih[g][1], a, 0, 0, 0);
          a = MFMA(xl0, bih[g][0], a, 0, 0, 0);
          a = MFMA(xl1, bih[g][1], a, 0, 0, 0);
          accx[0][g][wq * 64 + lane] = a;
        }
#pragma unroll
        for (int p = 0; p < 2; ++p) {
          const unsigned int* pq = seqp + xrow + (size_t)(p + 1) * HDIM;
          xpk[p][0] = *(const u32x4*)(pq + 8 * cg);
          xpk[p][1] = *(const u32x4*)(pq + 8 * cg + 4);
          xpk[p][2] = *(const u32x4*)(pq + 32 + 8 * cg);
          xpk[p][3] = *(const u32x4*)(pq + 32 + 8 * cg + 4);
        }
      }
    }
    __syncthreads();

    // A-waves own the serial recurrence: let the CU scheduler favor them (T5).
    if (isA) __builtin_amdgcn_s_setprio(1);

    for (int t = 0; t < T_LEN; t += 2) {
      STEP(t, 0);
      STEP(t + 1, 1);
    }

    if (isA) __builtin_amdgcn_s_setprio(0);

    // tail: store h(T-1) (written to planar parity 0 by step 511)
    if (!isA) {
#pragma unroll
      for (int r = 0; r < 4; ++r) {
        int mrow = 4 * cg + r;
        int ha = HADDR(mrow, uu >> 3) + (uu & 7);
        unsigned int hb =
            (unsigned int)__builtin_bit_cast(unsigned short, h_hi[0][ha])
          | ((unsigned int)__builtin_bit_cast(unsigned short, h_lo[0][ha]) << 16);
        seqp[((size_t)(bbase + mrow) * T_LEN + (T_LEN - 1)) * HDIM + uu] = hb;
      }
    }
}

// FC head: out[b] = fc2_b + fc2_w . relu(fc1_b + fc1_w . h_T[b])
__global__ __launch_bounds__(256, 1)
void fc_head(const unsigned int* __restrict__ seqp,
             const float* __restrict__ fc1_w, const float* __restrict__ fc1_b,
             const float* __restrict__ fc2_w, const float* __restrict__ fc2_b,
             float* __restrict__ out)
{
    __shared__ float w1[FC1 * HDIM];
    __shared__ float b1[FC1];
    __shared__ float w2[FC1];
    const int tid = threadIdx.x;
    for (int i = tid; i < FC1 * HDIM; i += 256) w1[i] = fc1_w[i];
    if (tid < FC1) { b1[tid] = fc1_b[tid]; w2[tid] = fc2_w[tid]; }
    __syncthreads();

    const int b = blockIdx.x * 256 + tid;
    const size_t base = ((size_t)b * T_LEN + (T_LEN - 1)) * HDIM;
    float h[HDIM];
#pragma unroll
    for (int q = 0; q < HDIM; ++q) {
      unsigned int v = seqp[base + q];
      float hi = (float)__builtin_bit_cast(__bf16, (unsigned short)(v & 0xffffu));
      float lo = (float)__builtin_bit_cast(__bf16, (unsigned short)(v >> 16));
      h[q] = hi + lo;
    }
    float acc2 = fc2_b[0];
    for (int m = 0; m < FC1; ++m) {
      float a = b1[m];
#pragma unroll
      for (int q = 0; q < HDIM; ++q) a += w1[m * HDIM + q] * h[q];
      acc2 += w2[m] * fmaxf(a, 0.0f);
    }
    out[b] = acc2;
}

extern "C" void kernel_launch(void* const* d_in, const int* in_sizes, int n_in,
                              void* d_out, int out_size, void* d_ws, size_t ws_size,
                              hipStream_t stream) {
    const float* x         = (const float*)d_in[0];
    const float* w_ih0     = (const float*)d_in[1];
    const float* w_ih_rest = (const float*)d_in[2];
    const float* w_hh      = (const float*)d_in[3];
    const float* b_ih      = (const float*)d_in[4];
    const float* b_hh      = (const float*)d_in[5];
    const float* fc1_w     = (const float*)d_in[6];
    const float* fc1_b     = (const float*)d_in[7];
    const float* fc2_w     = (const float*)d_in[8];
    const float* fc2_b     = (const float*)d_in[9];
    float* out = (float*)d_out;

    unsigned int* seqp = (unsigned int*)d_ws;   // [B,T,64] packed = 256 MiB

    lstm_mfma<true><<<dim3(B_TOT / 16), dim3(512), 0, stream>>>(
        x, w_ih0, w_hh, b_ih, b_hh, seqp);
    for (int l = 1; l < 5; ++l) {
      lstm_mfma<false><<<dim3(B_TOT / 16), dim3(512), 0, stream>>>(
          nullptr,
          w_ih_rest + (size_t)(l - 1) * 256 * HDIM,
          w_hh + (size_t)l * 256 * HDIM,
          b_ih + (size_t)l * 256,
          b_hh + (size_t)l * 256,
          seqp);
    }
    fc_head<<<dim3(B_TOT / 256), dim3(256), 0, stream>>>(
        seqp, fc1_w, fc1_b, fc2_w, fc2_b, out);
}

// Round 9
// 1974.256 us; speedup vs baseline: 3.3463x; 1.3130x over previous
//
#include <hip/hip_runtime.h>
#include <math.h>

#define B_TOT 2048
#define T_LEN 512
#define HDIM 64
#define FC1 50

typedef __bf16 bf16x8 __attribute__((ext_vector_type(8)));
typedef float f32x4 __attribute__((ext_vector_type(4)));
typedef unsigned int u32x4 __attribute__((ext_vector_type(4)));

// Fast transcendentals via raw ISA (no -ffast-math in harness: plain "/" emits
// v_div_scale/fmas/fixup ~12 insts; 20 divs/lane/step dominated the A-chain).
__device__ __forceinline__ float vrcp(float x) {
  float r; asm("v_rcp_f32 %0, %1" : "=v"(r) : "v"(x)); return r;
}
__device__ __forceinline__ float vexp2(float x) {
  float r; asm("v_exp_f32 %0, %1" : "=v"(r) : "v"(x)); return r;
}
__device__ __forceinline__ float sigm(float x) {
  return vrcp(1.0f + vexp2(x * -1.44269504088896340736f));
}
__device__ __forceinline__ float tanh_(float x) {
  return fmaf(2.0f, vrcp(1.0f + vexp2(x * -2.8853900817779268f)), -1.0f);
}

// lgkm-only barrier: LDS visibility without draining global loads/stores.
#define BARRIER() asm volatile("s_waitcnt lgkmcnt(0)\n\ts_barrier" ::: "memory")
#define MFMA __builtin_amdgcn_mfma_f32_16x16x32_bf16

// Planar h-exchange addressing: row-major [16][64] bf16 with 16B-chunk XOR
// swizzle (chunk ^= row&7): full-wave b128 access = uniform 8 lanes/bank-group.
#define HADDR(row, chunk) (((row) << 6) + ((((chunk) ^ ((row) & 7))) << 3))

__device__ __forceinline__ void unpk(u32x4 p0, u32x4 p1, bf16x8* hi, bf16x8* lo) {
  u32x4 h, l;
  h[0] = __builtin_amdgcn_perm(p0[1], p0[0], 0x05040100u);
  h[1] = __builtin_amdgcn_perm(p0[3], p0[2], 0x05040100u);
  h[2] = __builtin_amdgcn_perm(p1[1], p1[0], 0x05040100u);
  h[3] = __builtin_amdgcn_perm(p1[3], p1[2], 0x05040100u);
  l[0] = __builtin_amdgcn_perm(p0[1], p0[0], 0x07060302u);
  l[1] = __builtin_amdgcn_perm(p0[3], p0[2], 0x07060302u);
  l[2] = __builtin_amdgcn_perm(p1[1], p1[0], 0x07060302u);
  l[3] = __builtin_amdgcn_perm(p1[3], p1[2], 0x07060302u);
  *hi = __builtin_bit_cast(bf16x8, h);
  *lo = __builtin_bit_cast(bf16x8, l);
}

// Producer/consumer split LSTM step (R8 structure, fast-trans epilogue).
// Waves 0-3 (A, prio 1): recurrence — 4 planar ds_read_b128, 16 h-MFMAs seeded
//   from accx[P], v_rcp/v_exp gate epilogue, 8 ds_write_b16 planar h.
// Waves 4-7 (B): read planar h(t-1), pack, store to global seq; x-MFMAs for
//   t+1 into accx[1-P]; prefetch packed x(t+3).
#define STEP(T0, P)                                                            \
  {                                                                            \
    if (isA) {                                                                 \
      bf16x8 ahh0 = *(const bf16x8*)&h_hi[P][HADDR(nn, cg)];                   \
      bf16x8 ahh1 = *(const bf16x8*)&h_hi[P][HADDR(nn, 4 + cg)];               \
      bf16x8 ahl0 = *(const bf16x8*)&h_lo[P][HADDR(nn, cg)];                   \
      bf16x8 ahl1 = *(const bf16x8*)&h_lo[P][HADDR(nn, 4 + cg)];               \
      f32x4 accs[4];                                                           \
      _Pragma("unroll")                                                        \
      for (int g = 0; g < 4; ++g) {                                            \
        f32x4 a = accx[P][g][wq * 64 + lane];                                  \
        a = MFMA(ahh0, bhh[g][0], a, 0, 0, 0);                                 \
        a = MFMA(ahh1, bhh[g][1], a, 0, 0, 0);                                 \
        a = MFMA(ahl0, bhh[g][0], a, 0, 0, 0);                                 \
        a = MFMA(ahl1, bhh[g][1], a, 0, 0, 0);                                 \
        accs[g] = a;                                                           \
      }                                                                        \
      _Pragma("unroll")                                                        \
      for (int r = 0; r < 4; ++r) {                                            \
        float iv = sigm(accs[0][r]);                                           \
        float fv = sigm(accs[1][r]);                                           \
        float gv = tanh_(accs[2][r]);                                          \
        float ov = sigm(accs[3][r]);                                           \
        cell[r] = fv * cell[r] + iv * gv;                                      \
        float hv = ov * tanh_(cell[r]);                                        \
        __bf16 h1 = (__bf16)hv;                                                \
        __bf16 h2 = (__bf16)(hv - (float)h1);                                  \
        int mrow = 4 * cg + r;                                                 \
        int ha = HADDR(mrow, uu >> 3) + (uu & 7);                              \
        h_hi[1 - (P)][ha] = h1;                                                \
        h_lo[1 - (P)][ha] = h2;                                                \
      }                                                                        \
    } else {                                                                   \
      if ((T0) > 0) {                                                          \
        _Pragma("unroll")                                                      \
        for (int r = 0; r < 4; ++r) {                                          \
          int mrow = 4 * cg + r;                                               \
          int ha = HADDR(mrow, uu >> 3) + (uu & 7);                            \
          unsigned int hb =                                                    \
              (unsigned int)__builtin_bit_cast(unsigned short, h_hi[P][ha])    \
            | ((unsigned int)__builtin_bit_cast(unsigned short, h_lo[P][ha]) << 16); \
          seqp[((size_t)(bbase + mrow) * T_LEN + (T0) - 1) * HDIM + uu] = hb;  \
        }                                                                      \
      }                                                                        \
      if ((T0) + 1 < T_LEN) {                                                  \
        if (FIRST) {                                                           \
          _Pragma("unroll")                                                    \
          for (int g = 0; g < 4; ++g) {                                        \
            f32x4 a;                                                           \
            _Pragma("unroll")                                                  \
            for (int r = 0; r < 4; ++r)                                        \
              a[r] = bias[g] + xw[g*3+0] * xr[P][r*3+0]                        \
                             + xw[g*3+1] * xr[P][r*3+1]                        \
                             + xw[g*3+2] * xr[P][r*3+2];                       \
            accx[1 - (P)][g][wq * 64 + lane] = a;                              \
          }                                                                    \
        } else {                                                               \
          bf16x8 xh0, xl0, xh1, xl1;                                           \
          unpk(xpk[P][0], xpk[P][1], &xh0, &xl0);                              \
          unpk(xpk[P][2], xpk[P][3], &xh1, &xl1);                              \
          _Pragma("unroll")                                                    \
          for (int g = 0; g < 4; ++g) {                                        \
            f32x4 a = {bias[g], bias[g], bias[g], bias[g]};                    \
            a = MFMA(xh0, bih[g][0], a, 0, 0, 0);                              \
            a = MFMA(xh1, bih[g][1], a, 0, 0, 0);                              \
            a = MFMA(xl0, bih[g][0], a, 0, 0, 0);                              \
            a = MFMA(xl1, bih[g][1], a, 0, 0, 0);                              \
            accx[1 - (P)][g][wq * 64 + lane] = a;                              \
          }                                                                    \
        }                                                                      \
      }                                                                        \
      {                                                                        \
        int tp = (T0) + 3; if (tp >= T_LEN) tp = T_LEN - 1;                    \
        if (FIRST) {                                                           \
          _Pragma("unroll")                                                    \
          for (int r = 0; r < 4; ++r)                                          \
            _Pragma("unroll")                                                  \
            for (int i = 0; i < 3; ++i)                                        \
              xr[P][r*3+i] = x_f32[((size_t)(bbase + 4*cg + r) * T_LEN + tp) * 3 + i]; \
        } else {                                                               \
          const unsigned int* px = seqp + xrow + (size_t)tp * HDIM;            \
          xpk[P][0] = *(const u32x4*)(px + 8 * cg);                            \
          xpk[P][1] = *(const u32x4*)(px + 8 * cg + 4);                        \
          xpk[P][2] = *(const u32x4*)(px + 32 + 8 * cg);                       \
          xpk[P][3] = *(const u32x4*)(px + 32 + 8 * cg + 4);                   \
        }                                                                      \
      }                                                                        \
    }                                                                          \
    BARRIER();                                                                 \
  }

template<bool FIRST>
__global__ __launch_bounds__(512, 2)
void lstm_mfma(const float* __restrict__ x_f32,  // FIRST only: [B,T,3] f32
               const float* __restrict__ w_ih,   // FIRST: [256,3] else [256,64]
               const float* __restrict__ w_hh,   // [256,64]
               const float* __restrict__ b_ih,   // [256]
               const float* __restrict__ b_hh,   // [256]
               unsigned int* seqp)               // [B,T,64] packed hi|lo<<16 (in-place for mid)
{
    const int tid  = threadIdx.x;
    const int lane = tid & 63;
    const int wv   = tid >> 6;      // 0..7
    const bool isA = (wv < 4);
    const int wq   = wv & 3;        // unit-block index within group
    const int nn   = lane & 15;     // A-row m (batch) / B-col n (gate col)
    const int cg   = lane >> 4;     // k-group / D row group
    const int bbase = blockIdx.x * 16;
    const int grow = 16 * wq + nn;  // unit / gate-col index
    const int uu   = grow;

    __shared__ __align__(16) __bf16 h_hi[2][16 * 64];   // 2 KB, planar+swizzled
    __shared__ __align__(16) __bf16 h_lo[2][16 * 64];   // 2 KB
    __shared__ __align__(16) f32x4 accx[2][4][256];     // 32 KB

    // ---- weights ----
    bf16x8 bhh[4][2];
    bf16x8 bih[4][2];
    float xw[12];
    float bias[4];
    if (isA) {
#pragma unroll
      for (int g = 0; g < 4; ++g)
#pragma unroll
        for (int kk = 0; kk < 2; ++kk) {
          const float* wp = w_hh + (size_t)(64 * g + grow) * 64 + kk * 32 + 8 * cg;
          bf16x8 t;
#pragma unroll
          for (int e = 0; e < 8; ++e) t[e] = (__bf16)wp[e];
          bhh[g][kk] = t;
        }
    } else {
#pragma unroll
      for (int g = 0; g < 4; ++g) {
        int row = 64 * g + grow;
        bias[g] = b_ih[row] + b_hh[row];
      }
      if (FIRST) {
#pragma unroll
        for (int g = 0; g < 4; ++g)
#pragma unroll
          for (int i = 0; i < 3; ++i) xw[g * 3 + i] = w_ih[(64 * g + grow) * 3 + i];
      } else {
#pragma unroll
        for (int g = 0; g < 4; ++g)
#pragma unroll
          for (int kk = 0; kk < 2; ++kk) {
            const float* wp = w_ih + (size_t)(64 * g + grow) * 64 + kk * 32 + 8 * cg;
            bf16x8 t;
#pragma unroll
            for (int e = 0; e < 8; ++e) t[e] = (__bf16)wp[e];
            bih[g][kk] = t;
          }
      }
    }

    // zero h(-1) (both parities, both planes)
    for (int q = tid; q < 1024; q += 512) {
      h_hi[0][q] = (__bf16)0.f; h_hi[1][q] = (__bf16)0.f;
      h_lo[0][q] = (__bf16)0.f; h_lo[1][q] = (__bf16)0.f;
    }

    float cell[4] = {0.f, 0.f, 0.f, 0.f};

    const size_t xrow = (size_t)(bbase + nn) * T_LEN * HDIM;
    u32x4 xpk[2][4];
    float xr[2][12];

    if (!isA) {
      // ---- prologue: accx[0] from x(0); prime xr/xpk = x(1), x(2) ----
      if (FIRST) {
        float x0[12];
#pragma unroll
        for (int r = 0; r < 4; ++r)
#pragma unroll
          for (int i = 0; i < 3; ++i)
            x0[r*3+i] = x_f32[((size_t)(bbase + 4*cg + r) * T_LEN + 0) * 3 + i];
#pragma unroll
        for (int g = 0; g < 4; ++g) {
          f32x4 a;
#pragma unroll
          for (int r = 0; r < 4; ++r)
            a[r] = bias[g] + xw[g*3+0]*x0[r*3+0] + xw[g*3+1]*x0[r*3+1] + xw[g*3+2]*x0[r*3+2];
          accx[0][g][wq * 64 + lane] = a;
        }
#pragma unroll
        for (int p = 0; p < 2; ++p)
#pragma unroll
          for (int r = 0; r < 4; ++r)
#pragma unroll
            for (int i = 0; i < 3; ++i)
              xr[p][r*3+i] = x_f32[((size_t)(bbase + 4*cg + r) * T_LEN + (p + 1)) * 3 + i];
      } else {
        const unsigned int* px = seqp + xrow;
        u32x4 q0 = *(const u32x4*)(px + 8 * cg);
        u32x4 q1 = *(const u32x4*)(px + 8 * cg + 4);
        u32x4 q2 = *(const u32x4*)(px + 32 + 8 * cg);
        u32x4 q3 = *(const u32x4*)(px + 32 + 8 * cg + 4);
        bf16x8 xh0, xl0, xh1, xl1;
        unpk(q0, q1, &xh0, &xl0);
        unpk(q2, q3, &xh1, &xl1);
#pragma unroll
        for (int g = 0; g < 4; ++g) {
          f32x4 a = {bias[g], bias[g], bias[g], bias[g]};
          a = MFMA(xh0, bih[g][0], a, 0, 0, 0);
          a = MFMA(xh1, bih[g][1], a, 0, 0, 0);
          a = MFMA(xl0, bih[g][0], a, 0, 0, 0);
          a = MFMA(xl1, bih[g][1], a, 0, 0, 0);
          accx[0][g][wq * 64 + lane] = a;
        }
#pragma unroll
        for (int p = 0; p < 2; ++p) {
          const unsigned int* pq = seqp + xrow + (size_t)(p + 1) * HDIM;
          xpk[p][0] = *(const u32x4*)(pq + 8 * cg);
          xpk[p][1] = *(const u32x4*)(pq + 8 * cg + 4);
          xpk[p][2] = *(const u32x4*)(pq + 32 + 8 * cg);
          xpk[p][3] = *(const u32x4*)(pq + 32 + 8 * cg + 4);
        }
      }
    }
    __syncthreads();

    // A-waves own the serial recurrence: let the CU scheduler favor them (T5).
    if (isA) __builtin_amdgcn_s_setprio(1);

    for (int t = 0; t < T_LEN; t += 2) {
      STEP(t, 0);
      STEP(t + 1, 1);
    }

    if (isA) __builtin_amdgcn_s_setprio(0);

    // tail: store h(T-1) (written to planar parity 0 by step 511)
    if (!isA) {
#pragma unroll
      for (int r = 0; r < 4; ++r) {
        int mrow = 4 * cg + r;
        int ha = HADDR(mrow, uu >> 3) + (uu & 7);
        unsigned int hb =
            (unsigned int)__builtin_bit_cast(unsigned short, h_hi[0][ha])
          | ((unsigned int)__builtin_bit_cast(unsigned short, h_lo[0][ha]) << 16);
        seqp[((size_t)(bbase + mrow) * T_LEN + (T_LEN - 1)) * HDIM + uu] = hb;
      }
    }
}

// FC head: out[b] = fc2_b + fc2_w . relu(fc1_b + fc1_w . h_T[b])
__global__ __launch_bounds__(256, 1)
void fc_head(const unsigned int* __restrict__ seqp,
             const float* __restrict__ fc1_w, const float* __restrict__ fc1_b,
             const float* __restrict__ fc2_w, const float* __restrict__ fc2_b,
             float* __restrict__ out)
{
    __shared__ float w1[FC1 * HDIM];
    __shared__ float b1[FC1];
    __shared__ float w2[FC1];
    const int tid = threadIdx.x;
    for (int i = tid; i < FC1 * HDIM; i += 256) w1[i] = fc1_w[i];
    if (tid < FC1) { b1[tid] = fc1_b[tid]; w2[tid] = fc2_w[tid]; }
    __syncthreads();

    const int b = blockIdx.x * 256 + tid;
    const size_t base = ((size_t)b * T_LEN + (T_LEN - 1)) * HDIM;
    float h[HDIM];
#pragma unroll
    for (int q = 0; q < HDIM; ++q) {
      unsigned int v = seqp[base + q];
      float hi = (float)__builtin_bit_cast(__bf16, (unsigned short)(v & 0xffffu));
      float lo = (float)__builtin_bit_cast(__bf16, (unsigned short)(v >> 16));
      h[q] = hi + lo;
    }
    float acc2 = fc2_b[0];
    for (int m = 0; m < FC1; ++m) {
      float a = b1[m];
#pragma unroll
      for (int q = 0; q < HDIM; ++q) a += w1[m * HDIM + q] * h[q];
      acc2 += w2[m] * fmaxf(a, 0.0f);
    }
    out[b] = acc2;
}

extern "C" void kernel_launch(void* const* d_in, const int* in_sizes, int n_in,
                              void* d_out, int out_size, void* d_ws, size_t ws_size,
                              hipStream_t stream) {
    const float* x         = (const float*)d_in[0];
    const float* w_ih0     = (const float*)d_in[1];
    const float* w_ih_rest = (const float*)d_in[2];
    const float* w_hh      = (const float*)d_in[3];
    const float* b_ih      = (const float*)d_in[4];
    const float* b_hh      = (const float*)d_in[5];
    const float* fc1_w     = (const float*)d_in[6];
    const float* fc1_b     = (const float*)d_in[7];
    const float* fc2_w     = (const float*)d_in[8];
    const float* fc2_b     = (const float*)d_in[9];
    float* out = (float*)d_out;

    unsigned int* seqp = (unsigned int*)d_ws;   // [B,T,64] packed = 256 MiB

    lstm_mfma<true><<<dim3(B_TOT / 16), dim3(512), 0, stream>>>(
        x, w_ih0, w_hh, b_ih, b_hh, seqp);
    for (int l = 1; l < 5; ++l) {
      lstm_mfma<false><<<dim3(B_TOT / 16), dim3(512), 0, stream>>>(
          nullptr,
          w_ih_rest + (size_t)(l - 1) * 256 * HDIM,
          w_hh + (size_t)l * 256 * HDIM,
          b_ih + (size_t)l * 256,
          b_hh + (size_t)l * 256,
          seqp);
    }
    fc_head<<<dim3(B_TOT / 256), dim3(256), 0, stream>>>(
        seqp, fc1_w, fc1_b, fc2_w, fc2_b, out);
}